// Round 9
// baseline (759.391 us; speedup 1.0000x reference)
//
#include <hip/hip_runtime.h>
#include <hip/hip_bf16.h>
#include <math.h>

// Problem constants (B=2, I=8, J=1025, M=256, H=8, Dh=32)
#define BB   2
#define II   8
#define JJ   1025
#define MM   256
#define HH   8
#define DH   32
#define BI   (BB*II)          // 16
#define RTOT (BI*JJ)          // 16400 rows (tokens)
#define NQKV (3*MM)           // 768
#define HID  (4*MM)           // 1024
#define MPAD 16512            // 258*64

#define GRID 512              // 2 blocks/CU co-resident (54.9 KB LDS, <=256 VGPR)

#define WQN (NQKV*MM)         // 196608
#define W1N (HID*MM)          // 262144
#define W2N (MM*HID)          // 262144

typedef unsigned short ushort;
typedef __attribute__((ext_vector_type(8))) short short8;    // 8 bf16
typedef __attribute__((ext_vector_type(4))) float f32x4;
typedef __attribute__((ext_vector_type(4))) ushort ushort4v; // 4 bf16 (8 B)

__device__ __forceinline__ ushort f2bf(float x) {
    __hip_bfloat16 h = __float2bfloat16(x);
    return *reinterpret_cast<ushort*>(&h);
}
__device__ __forceinline__ float bf2f(ushort u) {
    __hip_bfloat16 h = *reinterpret_cast<__hip_bfloat16*>(&u);
    return __bfloat162float(h);
}
__device__ __forceinline__ float gelu_exact(float x) {
    return 0.5f * x * (1.0f + erff(x * 0.70710678118654752f));
}
__device__ __forceinline__ float wave_sum(float v) {
#pragma unroll
    for (int off = 32; off > 0; off >>= 1) v += __shfl_xor(v, off);
    return v;
}
__device__ __forceinline__ float block_sum256(float v, float* red, int t) {
    red[t] = v; __syncthreads();
    for (int s = 128; s > 0; s >>= 1) {
        if (t < s) red[t] += red[t + s];
        __syncthreads();
    }
    float r = red[0]; __syncthreads();
    return r;
}

// Single-use software grid barrier (counters zeroed by hipMemsetAsync before
// launch). Device-scope atomics cross XCDs; all GRID blocks are co-resident.
__device__ __forceinline__ void gbar(int* ctr) {
    __syncthreads();
    if (threadIdx.x == 0) {
        __threadfence();
        __hip_atomic_fetch_add(ctr, 1, __ATOMIC_RELEASE, __HIP_MEMORY_SCOPE_AGENT);
        while (__hip_atomic_load(ctr, __ATOMIC_ACQUIRE, __HIP_MEMORY_SCOPE_AGENT) < GRID)
            __builtin_amdgcn_s_sleep(2);
    }
    __syncthreads();
}

// Union'd LDS for all phases: max member = weff (54,912 B) -> 2 blocks/CU.
union __align__(16) Smem {
    struct { float red[256]; } p;                                   //  1 KB
    struct { ushort As[2][2560]; ushort Bs[2][2560]; } g;           // 20 KB (64*40)
    struct { ushort T1s[8448]; ushort WqS[8448]; ushort WvS[8448];
             float kv[1056]; } w;                                   // 54.9 KB (32*264, 32*33)
    struct { ushort sA[2][1280]; ushort sW[2][10240];
             float redS[128]; float redQ[128]; } a;                 // 46 KB (32*40, 256*40)
    struct { ushort sA[2][2560]; ushort sB[2][5120]; } f;           // 30 KB (64*40, 128*40)
};

// ---------------------------------------------------------------------------
// FC tile (proven 64x128x32 dbuf template), one output tile per call.
// ---------------------------------------------------------------------------
template <bool GELU_EPI, bool ADD_EPI, bool STORE_BF16, bool GUARD_M>
__device__ __forceinline__ void fc_tile(
    Smem& smu, int row0, int col0,
    const ushort* __restrict__ A, const ushort* __restrict__ W,
    const float* __restrict__ bias, const float* __restrict__ addsrc,
    void* __restrict__ Cout, int ldc, int K, int Mrows)
{
    auto& sf = smu.f;
    const int tid  = threadIdx.x;
    const int wave = tid >> 6;
    const int lane = tid & 63;
    const int lrow = lane & 15;
    const int quad = lane >> 4;
    const int ar = tid >> 2;
    const int ac = (tid & 3) * 8;
    const int KT = K / 32;

    __syncthreads();   // guard LDS reuse across items/phases

    f32x4 acc[4][2] = {};
    f32x4 ra, rb0, rb1;
    ra  = *(const f32x4*)(A + (size_t)(row0 + ar) * K + ac);
    rb0 = *(const f32x4*)(W + (size_t)(col0 + ar) * K + ac);
    rb1 = *(const f32x4*)(W + (size_t)(col0 + ar + 64) * K + ac);
    *(f32x4*)&sf.sA[0][ar * 40 + ac] = ra;
    *(f32x4*)&sf.sB[0][ar * 40 + ac] = rb0;
    *(f32x4*)&sf.sB[0][(ar + 64) * 40 + ac] = rb1;

    for (int kt = 0; kt < KT; ++kt) {
        __syncthreads();
        const int cur = kt & 1, nxt = cur ^ 1;
        const bool more = (kt + 1 < KT);
        if (more) {
            const int kk = (kt + 1) * 32;
            ra  = *(const f32x4*)(A + (size_t)(row0 + ar) * K + kk + ac);
            rb0 = *(const f32x4*)(W + (size_t)(col0 + ar) * K + kk + ac);
            rb1 = *(const f32x4*)(W + (size_t)(col0 + ar + 64) * K + kk + ac);
        }
        short8 fa[4], fb[2];
#pragma unroll
        for (int i = 0; i < 4; ++i)
            fa[i] = *(const short8*)&sf.sA[cur][(i * 16 + lrow) * 40 + quad * 8];
#pragma unroll
        for (int j = 0; j < 2; ++j)
            fb[j] = *(const short8*)&sf.sB[cur][(wave * 32 + j * 16 + lrow) * 40 + quad * 8];
#pragma unroll
        for (int i = 0; i < 4; ++i)
#pragma unroll
            for (int j = 0; j < 2; ++j)
                acc[i][j] = __builtin_amdgcn_mfma_f32_16x16x32_bf16(
                    fa[i], fb[j], acc[i][j], 0, 0, 0);
        if (more) {
            *(f32x4*)&sf.sA[nxt][ar * 40 + ac] = ra;
            *(f32x4*)&sf.sB[nxt][ar * 40 + ac] = rb0;
            *(f32x4*)&sf.sB[nxt][(ar + 64) * 40 + ac] = rb1;
        }
    }

#pragma unroll
    for (int i = 0; i < 4; ++i)
#pragma unroll
        for (int j = 0; j < 2; ++j) {
            const int ncol = col0 + wave * 32 + j * 16 + lrow;
            const float bv = bias ? bias[ncol] : 0.0f;
#pragma unroll
            for (int v = 0; v < 4; ++v) {
                const int r = row0 + i * 16 + quad * 4 + v;
                if (GUARD_M && r >= Mrows) continue;
                float c = acc[i][j][v] + bv;
                if (GELU_EPI) c = gelu_exact(c);
                if (ADD_EPI) c += addsrc[(size_t)r * ldc + ncol];
                if (STORE_BF16) ((ushort*)Cout)[(size_t)r * ldc + ncol] = f2bf(c);
                else            ((float*)Cout)[(size_t)r * ldc + ncol] = c;
            }
        }
}

// ---------------------------------------------------------------------------
// The single persistent kernel: 6 phases, 5 software grid barriers.
// ---------------------------------------------------------------------------
__global__ __launch_bounds__(256, 2) void k_fused(
    const float* __restrict__ save, const float* __restrict__ Wqkv,
    const float* __restrict__ Wo,
    const float* __restrict__ g1, const float* __restrict__ b1,
    const float* __restrict__ g2, const float* __restrict__ b2,
    const float* __restrict__ fc1w, const float* __restrict__ fc1b,
    const float* __restrict__ fc2w, const float* __restrict__ fc2b,
    float* __restrict__ out,
    ushort* __restrict__ Ah, ushort* __restrict__ Gm,
    ushort* __restrict__ WeffT, float* __restrict__ s2,
    ushort* __restrict__ Hbf, ushort* __restrict__ T,
    ushort* __restrict__ WqB, ushort* __restrict__ F1B,
    ushort* __restrict__ F2B, float* __restrict__ woSum,
    int* __restrict__ bar)
{
    __shared__ Smem sm;
    const int bid = blockIdx.x;
    const int G = GRID;
    const int t = threadIdx.x;

    // ================= Phase 0: prep (casts, wosum, Hbf pad, LN1) ==========
    for (int gb = bid; gb < 7312; gb += G) {
        if (gb < 2816) {
            int i = gb * 256 + t;
            if (i < WQN) WqB[i] = f2bf(Wqkv[i]);
            else if (i < WQN + W1N) F1B[i - WQN] = f2bf(fc1w[i - WQN]);
            else F2B[i - WQN - W1N] = f2bf(fc2w[i - WQN - W1N]);
        } else if (gb < 3072) {
            int m = gb - 2816;
            float s = block_sum256(Wo[m * MM + t], sm.p.red, t);
            if (t == 0) woSum[m] = s;
        } else if (gb < 3184) {
            int row = RTOT + (gb - 3072);
            Hbf[(size_t)row * MM + t] = 0;
        } else {
            const int wave = t >> 6, l = t & 63;
            const int row = (gb - 3184) * 4 + wave;
            const size_t base = (size_t)row * MM + 4 * l;
            if (row >= RTOT) {
                ushort4v z = 0; *(ushort4v*)&Ah[base] = z;
            } else {
                f32x4 v = *(const f32x4*)&save[base];
                float mu = wave_sum(v[0] + v[1] + v[2] + v[3]) * (1.0f / MM);
                f32x4 d;
#pragma unroll
                for (int c = 0; c < 4; ++c) d[c] = v[c] - mu;
                float var = wave_sum(d[0]*d[0] + d[1]*d[1] + d[2]*d[2] + d[3]*d[3]) * (1.0f / MM);
                float rstd = 1.0f / sqrtf(var + 1e-5f);
                f32x4 gg = *(const f32x4*)&g1[4 * l];
                f32x4 bb = *(const f32x4*)&b1[4 * l];
                ushort4v o;
#pragma unroll
                for (int c = 0; c < 4; ++c) o[c] = f2bf(d[c] * rstd * gg[c] + bb[c]);
                *(ushort4v*)&Ah[base] = o;
            }
        }
    }
    gbar(&bar[0]);

    // ================= Phase 1: Gram  G_bi = Ah_bi^T Ah_bi =================
    for (int wi = bid; wi < 256; wi += G) {
        __syncthreads();
        const int tile = wi & 15, bi = wi >> 4;
        const int m0 = (tile >> 2) * 64, n0 = (tile & 3) * 64;
        const int w = t >> 6, lane = t & 63;
        const int lrow = lane & 15, quad = lane >> 4;
        const int jj = t >> 3;
        const int mc = (t & 7) * 8;
        const ushort* base = Ah + (size_t)bi * JJ * MM;

        f32x4 acc[4] = {};
        f32x4 ra, rb;
        auto loadAB = [&](int j0) {
            int j = j0 + jj;
            if (j < JJ) {
                ra = *(const f32x4*)(base + (size_t)j * MM + m0 + mc);
                rb = *(const f32x4*)(base + (size_t)j * MM + n0 + mc);
            } else { ra = f32x4{0,0,0,0}; rb = f32x4{0,0,0,0}; }
        };
        auto stage = [&](int buf) {
            const ushort* pa = (const ushort*)&ra;
            const ushort* pb = (const ushort*)&rb;
#pragma unroll
            for (int e = 0; e < 8; ++e) {
                sm.g.As[buf][(mc + e) * 40 + jj] = pa[e];
                sm.g.Bs[buf][(mc + e) * 40 + jj] = pb[e];
            }
        };
        loadAB(0);
        stage(0);
        for (int ck = 0; ck < 33; ++ck) {
            __syncthreads();
            const int cur = ck & 1, nxt = cur ^ 1;
            const bool more = (ck + 1 < 33);
            if (more) loadAB((ck + 1) * 32);
            short8 fb = *(const short8*)&sm.g.Bs[cur][(w * 16 + lrow) * 40 + quad * 8];
#pragma unroll
            for (int mt = 0; mt < 4; ++mt) {
                short8 fa = *(const short8*)&sm.g.As[cur][(mt * 16 + lrow) * 40 + quad * 8];
                acc[mt] = __builtin_amdgcn_mfma_f32_16x16x32_bf16(fa, fb, acc[mt], 0, 0, 0);
            }
            if (more) stage(nxt);
        }
#pragma unroll
        for (int mt = 0; mt < 4; ++mt)
#pragma unroll
            for (int v = 0; v < 4; ++v) {
                int m = m0 + mt * 16 + quad * 4 + v;
                int n = n0 + w * 16 + lrow;
                Gm[((size_t)bi * MM + m) * MM + n] = f2bf(acc[mt][v]);
            }
    }
    gbar(&bar[1]);

    // ================= Phase 2: Weff per (bi,h) ============================
    for (int wi = bid; wi < 128; wi += G) {
        __syncthreads();
        const int bi = wi >> 3, h = wi & 7;
        const int w = t >> 6, lane = t & 63;
        const int lrow = lane & 15, quad = lane >> 4;
        const float scale = 0.17677669529663687f;  // 1/sqrt(32)
        {
            int r = t >> 3, c = (t & 7) * 32;
#pragma unroll
            for (int e = 0; e < 4; ++e) {
                *(f32x4*)&sm.w.WqS[r * 264 + c + e * 8] =
                    *(const f32x4*)(WqB + (size_t)(h * DH + r) * MM + c + e * 8);
                *(f32x4*)&sm.w.WvS[r * 264 + c + e * 8] =
                    *(const f32x4*)(WqB + (size_t)(2 * MM + h * DH + r) * MM + c + e * 8);
            }
        }
        f32x4 acc[2][4] = {};
        const ushort* wkbase = WqB + (size_t)(MM + h * DH) * MM;
        const ushort* gbase  = Gm + (size_t)bi * MM * MM;
        for (int kk = 0; kk < MM; kk += 32) {
            short8 fa[2], fb[4];
#pragma unroll
            for (int mt = 0; mt < 2; ++mt)
                fa[mt] = *(const short8*)(wkbase + (size_t)(mt * 16 + lrow) * MM + kk + quad * 8);
#pragma unroll
            for (int jt = 0; jt < 4; ++jt)
                fb[jt] = *(const short8*)(gbase + (size_t)((w * 4 + jt) * 16 + lrow) * MM + kk + quad * 8);
#pragma unroll
            for (int mt = 0; mt < 2; ++mt)
#pragma unroll
                for (int jt = 0; jt < 4; ++jt)
                    acc[mt][jt] = __builtin_amdgcn_mfma_f32_16x16x32_bf16(
                        fa[mt], fb[jt], acc[mt][jt], 0, 0, 0);
        }
#pragma unroll
        for (int mt = 0; mt < 2; ++mt)
#pragma unroll
            for (int jt = 0; jt < 4; ++jt)
#pragma unroll
                for (int v = 0; v < 4; ++v) {
                    int d1 = mt * 16 + quad * 4 + v;
                    int n  = (w * 4 + jt) * 16 + lrow;
                    sm.w.T1s[d1 * 264 + n] = f2bf(scale * acc[mt][jt][v]);
                }
        __syncthreads();
        {
            int d1 = t >> 3, d2b = (t & 7) * 4;
            float a4[4] = {0.f, 0.f, 0.f, 0.f};
            for (int n = 0; n < MM; ++n) {
                float tv = bf2f(sm.w.T1s[d1 * 264 + n]);
#pragma unroll
                for (int e = 0; e < 4; ++e)
                    a4[e] += tv * bf2f(sm.w.WvS[(d2b + e) * 264 + n]);
            }
#pragma unroll
            for (int e = 0; e < 4; ++e) sm.w.kv[d1 * 33 + d2b + e] = a4[e];
        }
        __syncthreads();
        {
            int d2 = t & 31, mb = (t >> 5) * 32;
            float kl[32];
#pragma unroll
            for (int d1 = 0; d1 < 32; ++d1) kl[d1] = sm.w.kv[d1 * 33 + d2];
            ushort* outp = WeffT + ((size_t)bi * MM + h * DH + d2) * MM + mb;
            for (int m = 0; m < 32; ++m) {
                float s = 0.f;
#pragma unroll
                for (int d1 = 0; d1 < 32; ++d1)
                    s += bf2f(sm.w.WqS[d1 * 264 + mb + m]) * kl[d1];
                outp[m] = f2bf(s);
            }
        }
    }
    gbar(&bar[2]);

    // ================= Phase 3: attn GEMM + s2 + LN2 -> Hbf ================
    for (int wi = bid; wi < 528; wi += G) {
        __syncthreads();
        const int jb = wi % 33, bi = wi / 33;
        const int w = t >> 6, lane = t & 63;
        const int lrow = lane & 15, quad = lane >> 4;
        const ushort* wbase = WeffT + (size_t)bi * MM * MM;
        const ushort* abase = Ah + (size_t)bi * JJ * MM;
        const int arow = (t & 127) >> 2, ak = (t & 3) * 8;
        const bool adut = (t < 128);
        const bool aval = adut && (jb * 32 + arow) < JJ;

        f32x4 rw[4], ra = {};
        auto loadW = [&](int kk) {
#pragma unroll
            for (int c = 0; c < 4; ++c)
                rw[c] = *(const f32x4*)(wbase + (size_t)t * MM + kk + c * 8);
            if (aval) ra = *(const f32x4*)(abase + (size_t)(jb * 32 + arow) * MM + kk + ak);
        };
        auto stage = [&](int buf) {
#pragma unroll
            for (int c = 0; c < 4; ++c)
                *(f32x4*)&sm.a.sW[buf][t * 40 + c * 8] = rw[c];
            if (adut) *(f32x4*)&sm.a.sA[buf][arow * 40 + ak] = aval ? ra : f32x4{0,0,0,0};
        };

        f32x4 acc[2][4] = {};
        loadW(0);
        stage(0);
        for (int kt = 0; kt < 8; ++kt) {
            __syncthreads();
            const int cur = kt & 1, nxt = cur ^ 1;
            const bool more = (kt + 1 < 8);
            if (more) loadW((kt + 1) * 32);
            short8 fa[2], fw[4];
#pragma unroll
            for (int i = 0; i < 2; ++i)
                fa[i] = *(const short8*)&sm.a.sA[cur][(i * 16 + lrow) * 40 + quad * 8];
#pragma unroll
            for (int jt = 0; jt < 4; ++jt)
                fw[jt] = *(const short8*)&sm.a.sW[cur][(w * 64 + jt * 16 + lrow) * 40 + quad * 8];
#pragma unroll
            for (int i = 0; i < 2; ++i)
#pragma unroll
                for (int jt = 0; jt < 4; ++jt)
                    acc[i][jt] = __builtin_amdgcn_mfma_f32_16x16x32_bf16(
                        fa[i], fw[jt], acc[i][jt], 0, 0, 0);
            if (more) stage(nxt);
        }

        int   colv[4];
        float wos[4], gv[4], bv[4];
#pragma unroll
        for (int jt = 0; jt < 4; ++jt) {
            colv[jt] = w * 64 + jt * 16 + lrow;
            wos[jt] = woSum[colv[jt]];
            gv[jt]  = g2[colv[jt]];
            bv[jt]  = b2[colv[jt]];
        }
        float pS[8], pQ[8];
#pragma unroll
        for (int i = 0; i < 2; ++i)
#pragma unroll
            for (int v = 0; v < 4; ++v) {
                int jv = jb * 32 + i * 16 + quad * 4 + v;
                bool valid = jv < JJ;
                size_t rbase = ((size_t)bi * JJ + (valid ? jv : 0)) * MM;
                float s = 0.f, q = 0.f;
#pragma unroll
                for (int jt = 0; jt < 4; ++jt) {
                    float c = 0.f;
                    if (valid)
                        c = wos[jt] * acc[i][jt][v] + save[rbase + colv[jt]];
                    acc[i][jt][v] = c;
                    s += c; q += c * c;
                }
#pragma unroll
                for (int off = 1; off < 16; off <<= 1) {
                    s += __shfl_xor(s, off);
                    q += __shfl_xor(q, off);
                }
                pS[i * 4 + v] = s; pQ[i * 4 + v] = q;
            }
        if (lrow == 0) {
#pragma unroll
            for (int i = 0; i < 2; ++i)
#pragma unroll
                for (int v = 0; v < 4; ++v) {
                    int rl = i * 16 + quad * 4 + v;
                    sm.a.redS[rl * 4 + w] = pS[i * 4 + v];
                    sm.a.redQ[rl * 4 + w] = pQ[i * 4 + v];
                }
        }
        __syncthreads();
#pragma unroll
        for (int i = 0; i < 2; ++i)
#pragma unroll
            for (int v = 0; v < 4; ++v) {
                int rl = i * 16 + quad * 4 + v;
                int jv = jb * 32 + rl;
                if (jv >= JJ) continue;
                float sum = sm.a.redS[rl * 4 + 0] + sm.a.redS[rl * 4 + 1]
                          + sm.a.redS[rl * 4 + 2] + sm.a.redS[rl * 4 + 3];
                float sq  = sm.a.redQ[rl * 4 + 0] + sm.a.redQ[rl * 4 + 1]
                          + sm.a.redQ[rl * 4 + 2] + sm.a.redQ[rl * 4 + 3];
                float mu = sum * (1.0f / MM);
                float var = sq * (1.0f / MM) - mu * mu;
                float rstd = rsqrtf(var + 1e-5f);
                size_t rbase = ((size_t)bi * JJ + jv) * MM;
#pragma unroll
                for (int jt = 0; jt < 4; ++jt) {
                    float c = acc[i][jt][v];
                    s2[rbase + colv[jt]] = c;
                    Hbf[rbase + colv[jt]] = f2bf((c - mu) * rstd * gv[jt] + bv[jt]);
                }
            }
    }
    gbar(&bar[3]);

    // ================= Phase 4: FC1  T = gelu(Hbf @ F1^T + b1) =============
    for (int wi = bid; wi < 2064; wi += G) {
        const int colt = wi & 7, rowt = wi >> 3;
        fc_tile<true, false, true, false>(sm, rowt * 64, colt * 128,
            Hbf, F1B, fc1b, nullptr, T, HID, MM, RTOT);
    }
    gbar(&bar[4]);

    // ================= Phase 5: FC2  out = T @ F2^T + b2 + s2 ==============
    for (int wi = bid; wi < 516; wi += G) {
        const int colt = wi & 1, rowt = wi >> 1;
        fc_tile<false, true, false, true>(sm, rowt * 64, colt * 128,
            T, F2B, fc2b, s2, out, MM, HID, RTOT);
    }
}

// ---------------------------------------------------------------------------
extern "C" void kernel_launch(void* const* d_in, const int* in_sizes, int n_in,
                              void* d_out, int out_size, void* d_ws, size_t ws_size,
                              hipStream_t stream) {
    const float* savespace = (const float*)d_in[1];
    const float* Wqkv      = (const float*)d_in[2];   // [768][256]
    const float* Wo        = (const float*)d_in[3];
    const float* ln1_g     = (const float*)d_in[4];
    const float* ln1_b     = (const float*)d_in[5];
    const float* ln2_g     = (const float*)d_in[6];
    const float* ln2_b     = (const float*)d_in[7];
    const float* fc1_w     = (const float*)d_in[8];   // [1024][256]
    const float* fc1_b     = (const float*)d_in[9];
    const float* fc2_w     = (const float*)d_in[10];  // [256][1024]
    const float* fc2_b     = (const float*)d_in[11];
    float* out = (float*)d_out;

    // ---- workspace layout (~73 MB, no aliasing; ws is 256 MB) ----
    char* w = (char*)d_ws;
    ushort* Ah    = (ushort*)w;                                   //  8,454,144
    ushort* Gm    = (ushort*)(w + 8454144);                       //  2,097,152
    ushort* WeffT = (ushort*)(w + 8454144 + 2097152);             //  2,097,152
    float*  s2    = (float*) (w + 8454144 + 2097152*2);           // 16,908,288
    ushort* Hbf   = (ushort*)(w + 8454144 + 2097152*2 + 16908288);//  8,454,144
    ushort* T     = (ushort*)(w + 8454144 + 2097152*2 + 16908288 + 8454144); // 33,816,576
    char* c4 = w + 8454144 + 2097152*2 + 16908288 + 8454144 + 33816576;
    ushort* WqB   = (ushort*)c4;                                  //    393,216
    ushort* F1B   = (ushort*)(c4 + WQN * 2);                      //    524,288
    ushort* F2B   = (ushort*)(c4 + WQN * 2 + W1N * 2);            //    524,288
    float*  woSum = (float*) (c4 + WQN * 2 + W1N * 2 + W2N * 2);  //      1,024
    int*    bar   = (int*)   (c4 + WQN * 2 + W1N * 2 + W2N * 2 + 1024 + 128);

    // zero the barrier counters (stream-ordered, graph-capturable)
    hipMemsetAsync(bar, 0, 8 * sizeof(int), stream);

    k_fused<<<dim3(GRID), dim3(256), 0, stream>>>(
        savespace, Wqkv, Wo, ln1_g, ln1_b, ln2_g, ln2_b,
        fc1_w, fc1_b, fc2_w, fc2_b, out,
        Ah, Gm, WeffT, s2, Hbf, T, WqB, F1B, F2B, woSum, bar);
}

// Round 10
// 468.992 us; speedup vs baseline: 1.6192x; 1.6192x over previous
//
#include <hip/hip_runtime.h>
#include <hip/hip_bf16.h>
#include <math.h>

// Problem constants (B=2, I=8, J=1025, M=256, H=8, Dh=32)
#define BB   2
#define II   8
#define JJ   1025
#define MM   256
#define HH   8
#define DH   32
#define BI   (BB*II)          // 16
#define RTOT (BI*JJ)          // 16400 rows (tokens)
#define NQKV (3*MM)           // 768
#define HID  (4*MM)           // 1024
#define MPAD 16512            // 258*64

#define GRID 512              // 2 blocks/CU co-resident (54.9 KB LDS, <=256 VGPR)

#define WQN (NQKV*MM)         // 196608
#define W1N (HID*MM)          // 262144
#define W2N (MM*HID)          // 262144

typedef unsigned short ushort;
typedef __attribute__((ext_vector_type(8))) short short8;    // 8 bf16
typedef __attribute__((ext_vector_type(4))) float f32x4;
typedef __attribute__((ext_vector_type(4))) ushort ushort4v; // 4 bf16 (8 B)

__device__ __forceinline__ ushort f2bf(float x) {
    __hip_bfloat16 h = __float2bfloat16(x);
    return *reinterpret_cast<ushort*>(&h);
}
__device__ __forceinline__ float bf2f(ushort u) {
    __hip_bfloat16 h = *reinterpret_cast<__hip_bfloat16*>(&u);
    return __bfloat162float(h);
}
__device__ __forceinline__ float gelu_exact(float x) {
    return 0.5f * x * (1.0f + erff(x * 0.70710678118654752f));
}
__device__ __forceinline__ float wave_sum(float v) {
#pragma unroll
    for (int off = 32; off > 0; off >>= 1) v += __shfl_xor(v, off);
    return v;
}
__device__ __forceinline__ float block_sum256(float v, float* red, int t) {
    red[t] = v; __syncthreads();
    for (int s = 128; s > 0; s >>= 1) {
        if (t < s) red[t] += red[t + s];
        __syncthreads();
    }
    float r = red[0]; __syncthreads();
    return r;
}

// Single-use software grid barrier. r9 lesson: ACQUIRE in the spin loop emits
// a cache invalidation PER POLL, trashing the co-resident block's L1 (FETCH
// 2x, 3x slowdown). Fix: RELEASE once on arrival, RELAXED polls with sleep
// backoff, ONE ACQUIRE after exit for the ordering/invalidations we need.
__device__ __forceinline__ void gbar(int* ctr) {
    __syncthreads();
    if (threadIdx.x == 0) {
        __hip_atomic_fetch_add(ctr, 1, __ATOMIC_RELEASE, __HIP_MEMORY_SCOPE_AGENT);
        while (__hip_atomic_load(ctr, __ATOMIC_RELAXED, __HIP_MEMORY_SCOPE_AGENT) < GRID)
            __builtin_amdgcn_s_sleep(16);
        (void)__hip_atomic_load(ctr, __ATOMIC_ACQUIRE, __HIP_MEMORY_SCOPE_AGENT);
    }
    __syncthreads();
}

// Union'd LDS for all phases: max member = weff (54,912 B) -> 2 blocks/CU.
union __align__(16) Smem {
    struct { float red[256]; } p;                                   //  1 KB
    struct { ushort As[2][2560]; ushort Bs[2][2560]; } g;           // 20 KB (64*40)
    struct { ushort T1s[8448]; ushort WqS[8448]; ushort WvS[8448];
             float kv[1056]; } w;                                   // 54.9 KB (32*264, 32*33)
    struct { ushort sA[2][1280]; ushort sW[2][10240];
             float redS[128]; float redQ[128]; } a;                 // 46 KB (32*40, 256*40)
    struct { ushort sA[2][2560]; ushort sB[2][5120]; } f;           // 30 KB (64*40, 128*40)
};

// ---------------------------------------------------------------------------
// FC tile (proven 64x128x32 dbuf template), one output tile per call.
// ---------------------------------------------------------------------------
template <bool GELU_EPI, bool ADD_EPI, bool STORE_BF16, bool GUARD_M>
__device__ __forceinline__ void fc_tile(
    Smem& smu, int row0, int col0,
    const ushort* __restrict__ A, const ushort* __restrict__ W,
    const float* __restrict__ bias, const float* __restrict__ addsrc,
    void* __restrict__ Cout, int ldc, int K, int Mrows)
{
    auto& sf = smu.f;
    const int tid  = threadIdx.x;
    const int wave = tid >> 6;
    const int lane = tid & 63;
    const int lrow = lane & 15;
    const int quad = lane >> 4;
    const int ar = tid >> 2;
    const int ac = (tid & 3) * 8;
    const int KT = K / 32;

    __syncthreads();   // guard LDS reuse across items/phases

    f32x4 acc[4][2] = {};
    f32x4 ra, rb0, rb1;
    ra  = *(const f32x4*)(A + (size_t)(row0 + ar) * K + ac);
    rb0 = *(const f32x4*)(W + (size_t)(col0 + ar) * K + ac);
    rb1 = *(const f32x4*)(W + (size_t)(col0 + ar + 64) * K + ac);
    *(f32x4*)&sf.sA[0][ar * 40 + ac] = ra;
    *(f32x4*)&sf.sB[0][ar * 40 + ac] = rb0;
    *(f32x4*)&sf.sB[0][(ar + 64) * 40 + ac] = rb1;

    for (int kt = 0; kt < KT; ++kt) {
        __syncthreads();
        const int cur = kt & 1, nxt = cur ^ 1;
        const bool more = (kt + 1 < KT);
        if (more) {
            const int kk = (kt + 1) * 32;
            ra  = *(const f32x4*)(A + (size_t)(row0 + ar) * K + kk + ac);
            rb0 = *(const f32x4*)(W + (size_t)(col0 + ar) * K + kk + ac);
            rb1 = *(const f32x4*)(W + (size_t)(col0 + ar + 64) * K + kk + ac);
        }
        short8 fa[4], fb[2];
#pragma unroll
        for (int i = 0; i < 4; ++i)
            fa[i] = *(const short8*)&sf.sA[cur][(i * 16 + lrow) * 40 + quad * 8];
#pragma unroll
        for (int j = 0; j < 2; ++j)
            fb[j] = *(const short8*)&sf.sB[cur][(wave * 32 + j * 16 + lrow) * 40 + quad * 8];
#pragma unroll
        for (int i = 0; i < 4; ++i)
#pragma unroll
            for (int j = 0; j < 2; ++j)
                acc[i][j] = __builtin_amdgcn_mfma_f32_16x16x32_bf16(
                    fa[i], fb[j], acc[i][j], 0, 0, 0);
        if (more) {
            *(f32x4*)&sf.sA[nxt][ar * 40 + ac] = ra;
            *(f32x4*)&sf.sB[nxt][ar * 40 + ac] = rb0;
            *(f32x4*)&sf.sB[nxt][(ar + 64) * 40 + ac] = rb1;
        }
    }

#pragma unroll
    for (int i = 0; i < 4; ++i)
#pragma unroll
        for (int j = 0; j < 2; ++j) {
            const int ncol = col0 + wave * 32 + j * 16 + lrow;
            const float bv = bias ? bias[ncol] : 0.0f;
#pragma unroll
            for (int v = 0; v < 4; ++v) {
                const int r = row0 + i * 16 + quad * 4 + v;
                if (GUARD_M && r >= Mrows) continue;
                float c = acc[i][j][v] + bv;
                if (GELU_EPI) c = gelu_exact(c);
                if (ADD_EPI) c += addsrc[(size_t)r * ldc + ncol];
                if (STORE_BF16) ((ushort*)Cout)[(size_t)r * ldc + ncol] = f2bf(c);
                else            ((float*)Cout)[(size_t)r * ldc + ncol] = c;
            }
        }
}

// ---------------------------------------------------------------------------
// The single persistent kernel: 6 phases, 5 software grid barriers.
// ---------------------------------------------------------------------------
__global__ __launch_bounds__(256, 2) void k_fused(
    const float* __restrict__ save, const float* __restrict__ Wqkv,
    const float* __restrict__ Wo,
    const float* __restrict__ g1, const float* __restrict__ b1,
    const float* __restrict__ g2, const float* __restrict__ b2,
    const float* __restrict__ fc1w, const float* __restrict__ fc1b,
    const float* __restrict__ fc2w, const float* __restrict__ fc2b,
    float* __restrict__ out,
    ushort* __restrict__ Ah, ushort* __restrict__ Gm,
    ushort* __restrict__ WeffT, float* __restrict__ s2,
    ushort* __restrict__ Hbf, ushort* __restrict__ T,
    ushort* __restrict__ WqB, ushort* __restrict__ F1B,
    ushort* __restrict__ F2B, float* __restrict__ woSum,
    int* __restrict__ bar)
{
    __shared__ Smem sm;
    const int bid = blockIdx.x;
    const int G = GRID;
    const int t = threadIdx.x;

    // ================= Phase 0: prep (casts, wosum, Hbf pad, LN1) ==========
    for (int gb = bid; gb < 7312; gb += G) {
        if (gb < 2816) {
            int i = gb * 256 + t;
            if (i < WQN) WqB[i] = f2bf(Wqkv[i]);
            else if (i < WQN + W1N) F1B[i - WQN] = f2bf(fc1w[i - WQN]);
            else F2B[i - WQN - W1N] = f2bf(fc2w[i - WQN - W1N]);
        } else if (gb < 3072) {
            int m = gb - 2816;
            float s = block_sum256(Wo[m * MM + t], sm.p.red, t);
            if (t == 0) woSum[m] = s;
        } else if (gb < 3184) {
            int row = RTOT + (gb - 3072);
            Hbf[(size_t)row * MM + t] = 0;
        } else {
            const int wave = t >> 6, l = t & 63;
            const int row = (gb - 3184) * 4 + wave;
            const size_t base = (size_t)row * MM + 4 * l;
            if (row >= RTOT) {
                ushort4v z = 0; *(ushort4v*)&Ah[base] = z;
            } else {
                f32x4 v = *(const f32x4*)&save[base];
                float mu = wave_sum(v[0] + v[1] + v[2] + v[3]) * (1.0f / MM);
                f32x4 d;
#pragma unroll
                for (int c = 0; c < 4; ++c) d[c] = v[c] - mu;
                float var = wave_sum(d[0]*d[0] + d[1]*d[1] + d[2]*d[2] + d[3]*d[3]) * (1.0f / MM);
                float rstd = 1.0f / sqrtf(var + 1e-5f);
                f32x4 gg = *(const f32x4*)&g1[4 * l];
                f32x4 bb = *(const f32x4*)&b1[4 * l];
                ushort4v o;
#pragma unroll
                for (int c = 0; c < 4; ++c) o[c] = f2bf(d[c] * rstd * gg[c] + bb[c]);
                *(ushort4v*)&Ah[base] = o;
            }
        }
    }
    gbar(&bar[0]);

    // ================= Phase 1: Gram  G_bi = Ah_bi^T Ah_bi =================
    for (int wi = bid; wi < 256; wi += G) {
        __syncthreads();
        const int tile = wi & 15, bi = wi >> 4;
        const int m0 = (tile >> 2) * 64, n0 = (tile & 3) * 64;
        const int w = t >> 6, lane = t & 63;
        const int lrow = lane & 15, quad = lane >> 4;
        const int jj = t >> 3;
        const int mc = (t & 7) * 8;
        const ushort* base = Ah + (size_t)bi * JJ * MM;

        f32x4 acc[4] = {};
        f32x4 ra, rb;
        auto loadAB = [&](int j0) {
            int j = j0 + jj;
            if (j < JJ) {
                ra = *(const f32x4*)(base + (size_t)j * MM + m0 + mc);
                rb = *(const f32x4*)(base + (size_t)j * MM + n0 + mc);
            } else { ra = f32x4{0,0,0,0}; rb = f32x4{0,0,0,0}; }
        };
        auto stage = [&](int buf) {
            const ushort* pa = (const ushort*)&ra;
            const ushort* pb = (const ushort*)&rb;
#pragma unroll
            for (int e = 0; e < 8; ++e) {
                sm.g.As[buf][(mc + e) * 40 + jj] = pa[e];
                sm.g.Bs[buf][(mc + e) * 40 + jj] = pb[e];
            }
        };
        loadAB(0);
        stage(0);
        for (int ck = 0; ck < 33; ++ck) {
            __syncthreads();
            const int cur = ck & 1, nxt = cur ^ 1;
            const bool more = (ck + 1 < 33);
            if (more) loadAB((ck + 1) * 32);
            short8 fb = *(const short8*)&sm.g.Bs[cur][(w * 16 + lrow) * 40 + quad * 8];
#pragma unroll
            for (int mt = 0; mt < 4; ++mt) {
                short8 fa = *(const short8*)&sm.g.As[cur][(mt * 16 + lrow) * 40 + quad * 8];
                acc[mt] = __builtin_amdgcn_mfma_f32_16x16x32_bf16(fa, fb, acc[mt], 0, 0, 0);
            }
            if (more) stage(nxt);
        }
#pragma unroll
        for (int mt = 0; mt < 4; ++mt)
#pragma unroll
            for (int v = 0; v < 4; ++v) {
                int m = m0 + mt * 16 + quad * 4 + v;
                int n = n0 + w * 16 + lrow;
                Gm[((size_t)bi * MM + m) * MM + n] = f2bf(acc[mt][v]);
            }
    }
    gbar(&bar[1]);

    // ================= Phase 2: Weff per (bi,h) ============================
    for (int wi = bid; wi < 128; wi += G) {
        __syncthreads();
        const int bi = wi >> 3, h = wi & 7;
        const int w = t >> 6, lane = t & 63;
        const int lrow = lane & 15, quad = lane >> 4;
        const float scale = 0.17677669529663687f;  // 1/sqrt(32)
        {
            int r = t >> 3, c = (t & 7) * 32;
#pragma unroll
            for (int e = 0; e < 4; ++e) {
                *(f32x4*)&sm.w.WqS[r * 264 + c + e * 8] =
                    *(const f32x4*)(WqB + (size_t)(h * DH + r) * MM + c + e * 8);
                *(f32x4*)&sm.w.WvS[r * 264 + c + e * 8] =
                    *(const f32x4*)(WqB + (size_t)(2 * MM + h * DH + r) * MM + c + e * 8);
            }
        }
        f32x4 acc[2][4] = {};
        const ushort* wkbase = WqB + (size_t)(MM + h * DH) * MM;
        const ushort* gbase  = Gm + (size_t)bi * MM * MM;
        for (int kk = 0; kk < MM; kk += 32) {
            short8 fa[2], fb[4];
#pragma unroll
            for (int mt = 0; mt < 2; ++mt)
                fa[mt] = *(const short8*)(wkbase + (size_t)(mt * 16 + lrow) * MM + kk + quad * 8);
#pragma unroll
            for (int jt = 0; jt < 4; ++jt)
                fb[jt] = *(const short8*)(gbase + (size_t)((w * 4 + jt) * 16 + lrow) * MM + kk + quad * 8);
#pragma unroll
            for (int mt = 0; mt < 2; ++mt)
#pragma unroll
                for (int jt = 0; jt < 4; ++jt)
                    acc[mt][jt] = __builtin_amdgcn_mfma_f32_16x16x32_bf16(
                        fa[mt], fb[jt], acc[mt][jt], 0, 0, 0);
        }
#pragma unroll
        for (int mt = 0; mt < 2; ++mt)
#pragma unroll
            for (int jt = 0; jt < 4; ++jt)
#pragma unroll
                for (int v = 0; v < 4; ++v) {
                    int d1 = mt * 16 + quad * 4 + v;
                    int n  = (w * 4 + jt) * 16 + lrow;
                    sm.w.T1s[d1 * 264 + n] = f2bf(scale * acc[mt][jt][v]);
                }
        __syncthreads();
        {
            int d1 = t >> 3, d2b = (t & 7) * 4;
            float a4[4] = {0.f, 0.f, 0.f, 0.f};
            for (int n = 0; n < MM; ++n) {
                float tv = bf2f(sm.w.T1s[d1 * 264 + n]);
#pragma unroll
                for (int e = 0; e < 4; ++e)
                    a4[e] += tv * bf2f(sm.w.WvS[(d2b + e) * 264 + n]);
            }
#pragma unroll
            for (int e = 0; e < 4; ++e) sm.w.kv[d1 * 33 + d2b + e] = a4[e];
        }
        __syncthreads();
        {
            int d2 = t & 31, mb = (t >> 5) * 32;
            float kl[32];
#pragma unroll
            for (int d1 = 0; d1 < 32; ++d1) kl[d1] = sm.w.kv[d1 * 33 + d2];
            ushort* outp = WeffT + ((size_t)bi * MM + h * DH + d2) * MM + mb;
            for (int m = 0; m < 32; ++m) {
                float s = 0.f;
#pragma unroll
                for (int d1 = 0; d1 < 32; ++d1)
                    s += bf2f(sm.w.WqS[d1 * 264 + mb + m]) * kl[d1];
                outp[m] = f2bf(s);
            }
        }
    }
    gbar(&bar[2]);

    // ================= Phase 3: attn GEMM + s2 + LN2 -> Hbf ================
    for (int wi = bid; wi < 528; wi += G) {
        __syncthreads();
        const int jb = wi % 33, bi = wi / 33;
        const int w = t >> 6, lane = t & 63;
        const int lrow = lane & 15, quad = lane >> 4;
        const ushort* wbase = WeffT + (size_t)bi * MM * MM;
        const ushort* abase = Ah + (size_t)bi * JJ * MM;
        const int arow = (t & 127) >> 2, ak = (t & 3) * 8;
        const bool adut = (t < 128);
        const bool aval = adut && (jb * 32 + arow) < JJ;

        f32x4 rw[4], ra = {};
        auto loadW = [&](int kk) {
#pragma unroll
            for (int c = 0; c < 4; ++c)
                rw[c] = *(const f32x4*)(wbase + (size_t)t * MM + kk + c * 8);
            if (aval) ra = *(const f32x4*)(abase + (size_t)(jb * 32 + arow) * MM + kk + ak);
        };
        auto stage = [&](int buf) {
#pragma unroll
            for (int c = 0; c < 4; ++c)
                *(f32x4*)&sm.a.sW[buf][t * 40 + c * 8] = rw[c];
            if (adut) *(f32x4*)&sm.a.sA[buf][arow * 40 + ak] = aval ? ra : f32x4{0,0,0,0};
        };

        f32x4 acc[2][4] = {};
        loadW(0);
        stage(0);
        for (int kt = 0; kt < 8; ++kt) {
            __syncthreads();
            const int cur = kt & 1, nxt = cur ^ 1;
            const bool more = (kt + 1 < 8);
            if (more) loadW((kt + 1) * 32);
            short8 fa[2], fw[4];
#pragma unroll
            for (int i = 0; i < 2; ++i)
                fa[i] = *(const short8*)&sm.a.sA[cur][(i * 16 + lrow) * 40 + quad * 8];
#pragma unroll
            for (int jt = 0; jt < 4; ++jt)
                fw[jt] = *(const short8*)&sm.a.sW[cur][(w * 64 + jt * 16 + lrow) * 40 + quad * 8];
#pragma unroll
            for (int i = 0; i < 2; ++i)
#pragma unroll
                for (int jt = 0; jt < 4; ++jt)
                    acc[i][jt] = __builtin_amdgcn_mfma_f32_16x16x32_bf16(
                        fa[i], fw[jt], acc[i][jt], 0, 0, 0);
            if (more) stage(nxt);
        }

        int   colv[4];
        float wos[4], gv[4], bv[4];
#pragma unroll
        for (int jt = 0; jt < 4; ++jt) {
            colv[jt] = w * 64 + jt * 16 + lrow;
            wos[jt] = woSum[colv[jt]];
            gv[jt]  = g2[colv[jt]];
            bv[jt]  = b2[colv[jt]];
        }
        float pS[8], pQ[8];
#pragma unroll
        for (int i = 0; i < 2; ++i)
#pragma unroll
            for (int v = 0; v < 4; ++v) {
                int jv = jb * 32 + i * 16 + quad * 4 + v;
                bool valid = jv < JJ;
                size_t rbase = ((size_t)bi * JJ + (valid ? jv : 0)) * MM;
                float s = 0.f, q = 0.f;
#pragma unroll
                for (int jt = 0; jt < 4; ++jt) {
                    float c = 0.f;
                    if (valid)
                        c = wos[jt] * acc[i][jt][v] + save[rbase + colv[jt]];
                    acc[i][jt][v] = c;
                    s += c; q += c * c;
                }
#pragma unroll
                for (int off = 1; off < 16; off <<= 1) {
                    s += __shfl_xor(s, off);
                    q += __shfl_xor(q, off);
                }
                pS[i * 4 + v] = s; pQ[i * 4 + v] = q;
            }
        if (lrow == 0) {
#pragma unroll
            for (int i = 0; i < 2; ++i)
#pragma unroll
                for (int v = 0; v < 4; ++v) {
                    int rl = i * 16 + quad * 4 + v;
                    sm.a.redS[rl * 4 + w] = pS[i * 4 + v];
                    sm.a.redQ[rl * 4 + w] = pQ[i * 4 + v];
                }
        }
        __syncthreads();
#pragma unroll
        for (int i = 0; i < 2; ++i)
#pragma unroll
            for (int v = 0; v < 4; ++v) {
                int rl = i * 16 + quad * 4 + v;
                int jv = jb * 32 + rl;
                if (jv >= JJ) continue;
                float sum = sm.a.redS[rl * 4 + 0] + sm.a.redS[rl * 4 + 1]
                          + sm.a.redS[rl * 4 + 2] + sm.a.redS[rl * 4 + 3];
                float sq  = sm.a.redQ[rl * 4 + 0] + sm.a.redQ[rl * 4 + 1]
                          + sm.a.redQ[rl * 4 + 2] + sm.a.redQ[rl * 4 + 3];
                float mu = sum * (1.0f / MM);
                float var = sq * (1.0f / MM) - mu * mu;
                float rstd = rsqrtf(var + 1e-5f);
                size_t rbase = ((size_t)bi * JJ + jv) * MM;
#pragma unroll
                for (int jt = 0; jt < 4; ++jt) {
                    float c = acc[i][jt][v];
                    s2[rbase + colv[jt]] = c;
                    Hbf[rbase + colv[jt]] = f2bf((c - mu) * rstd * gv[jt] + bv[jt]);
                }
            }
    }
    gbar(&bar[3]);

    // ================= Phase 4: FC1  T = gelu(Hbf @ F1^T + b1) =============
    for (int wi = bid; wi < 2064; wi += G) {
        const int colt = wi & 7, rowt = wi >> 3;
        fc_tile<true, false, true, false>(sm, rowt * 64, colt * 128,
            Hbf, F1B, fc1b, nullptr, T, HID, MM, RTOT);
    }
    gbar(&bar[4]);

    // ================= Phase 5: FC2  out = T @ F2^T + b2 + s2 ==============
    for (int wi = bid; wi < 516; wi += G) {
        const int colt = wi & 1, rowt = wi >> 1;
        fc_tile<false, true, false, true>(sm, rowt * 64, colt * 128,
            T, F2B, fc2b, s2, out, MM, HID, RTOT);
    }
}

// ---------------------------------------------------------------------------
extern "C" void kernel_launch(void* const* d_in, const int* in_sizes, int n_in,
                              void* d_out, int out_size, void* d_ws, size_t ws_size,
                              hipStream_t stream) {
    const float* savespace = (const float*)d_in[1];
    const float* Wqkv      = (const float*)d_in[2];   // [768][256]
    const float* Wo        = (const float*)d_in[3];
    const float* ln1_g     = (const float*)d_in[4];
    const float* ln1_b     = (const float*)d_in[5];
    const float* ln2_g     = (const float*)d_in[6];
    const float* ln2_b     = (const float*)d_in[7];
    const float* fc1_w     = (const float*)d_in[8];   // [1024][256]
    const float* fc1_b     = (const float*)d_in[9];
    const float* fc2_w     = (const float*)d_in[10];  // [256][1024]
    const float* fc2_b     = (const float*)d_in[11];
    float* out = (float*)d_out;

    // ---- workspace layout (~73 MB, no aliasing; ws is 256 MB) ----
    char* w = (char*)d_ws;
    ushort* Ah    = (ushort*)w;                                   //  8,454,144
    ushort* Gm    = (ushort*)(w + 8454144);                       //  2,097,152
    ushort* WeffT = (ushort*)(w + 8454144 + 2097152);             //  2,097,152
    float*  s2    = (float*) (w + 8454144 + 2097152*2);           // 16,908,288
    ushort* Hbf   = (ushort*)(w + 8454144 + 2097152*2 + 16908288);//  8,454,144
    ushort* T     = (ushort*)(w + 8454144 + 2097152*2 + 16908288 + 8454144); // 33,816,576
    char* c4 = w + 8454144 + 2097152*2 + 16908288 + 8454144 + 33816576;
    ushort* WqB   = (ushort*)c4;                                  //    393,216
    ushort* F1B   = (ushort*)(c4 + WQN * 2);                      //    524,288
    ushort* F2B   = (ushort*)(c4 + WQN * 2 + W1N * 2);            //    524,288
    float*  woSum = (float*) (c4 + WQN * 2 + W1N * 2 + W2N * 2);  //      1,024
    int*    bar   = (int*)   (c4 + WQN * 2 + W1N * 2 + W2N * 2 + 1024 + 128);

    // zero the barrier counters (stream-ordered, graph-capturable)
    hipMemsetAsync(bar, 0, 8 * sizeof(int), stream);

    k_fused<<<dim3(GRID), dim3(256), 0, stream>>>(
        savespace, Wqkv, Wo, ln1_g, ln1_b, ln2_g, ln2_b,
        fc1_w, fc1_b, fc2_w, fc2_b, out,
        Ah, Gm, WeffT, s2, Hbf, T, WqB, F1B, F2B, woSum, bar);
}